// Round 1
// baseline (397.715 us; speedup 1.0000x reference)
//
#include <hip/hip_runtime.h>

typedef __attribute__((ext_vector_type(8)))  short short8;
typedef __attribute__((ext_vector_type(4)))  short short4v;
typedef __attribute__((ext_vector_type(4)))  float f32x4;
typedef __attribute__((ext_vector_type(16))) float f32x16;
typedef __attribute__((ext_vector_type(4)))  int   int4v;

__device__ inline short f2bf(float f) {
  unsigned u = __float_as_uint(f);
  u += 0x7fffu + ((u >> 16) & 1u);   // RNE to bf16
  return (short)(u >> 16);
}

// ---------------- fp32 -> bf16 weight conversion ----------------
__global__ void cvt_kernel(const float* __restrict__ in, short* __restrict__ out, int n4) {
  int i = blockIdx.x * blockDim.x + threadIdx.x;
  int stride = gridDim.x * blockDim.x;
  for (; i < n4; i += stride) {
    f32x4 v = ((const f32x4*)in)[i];
    short4v o;
    o[0] = f2bf(v[0]); o[1] = f2bf(v[1]); o[2] = f2bf(v[2]); o[3] = f2bf(v[3]);
    ((short4v*)out)[i] = o;
  }
}

// ---------------- stage 1: out1[b,k,q] = sum_p x[b,k*256+p] * w1[k,q,p] ----------------
// writes shuffled bf16 intermediate: inter[b][l][r], l = q&15, r = k*16 + (q>>4)
__global__ __launch_bounds__(256) void stage1_kernel(
    const float* __restrict__ x, const short* __restrict__ w1b, short* __restrict__ inter) {
  const int lane = threadIdx.x & 63;
  const int wq   = threadIdx.x >> 6;    // wave 0..3 -> q range
  const int b0   = blockIdx.x * 64;
  const int k    = blockIdx.y;          // 0..15
  const int q0w  = wq * 64;
  const int lr   = lane & 15;
  const int kid  = lane >> 4;           // 0..3

  f32x4 acc[4][4] = {};
  const float* xbase = x   + (size_t)(b0 + lr) * 4096 + k * 256 + kid * 8;
  const short* wbase = w1b + k * 65536 + (q0w + lr) * 256 + kid * 8;

  #pragma unroll
  for (int kk = 0; kk < 256; kk += 32) {
    short8 a[4], b[4];
    #pragma unroll
    for (int mt = 0; mt < 4; ++mt) {
      const f32x4* ap = (const f32x4*)(xbase + (size_t)mt * 16 * 4096 + kk);
      f32x4 lo = ap[0], hi = ap[1];
      short8 av;
      av[0] = f2bf(lo[0]); av[1] = f2bf(lo[1]); av[2] = f2bf(lo[2]); av[3] = f2bf(lo[3]);
      av[4] = f2bf(hi[0]); av[5] = f2bf(hi[1]); av[6] = f2bf(hi[2]); av[7] = f2bf(hi[3]);
      a[mt] = av;
    }
    #pragma unroll
    for (int nt = 0; nt < 4; ++nt)
      b[nt] = *(const short8*)(wbase + nt * 16 * 256 + kk);
    #pragma unroll
    for (int mt = 0; mt < 4; ++mt)
      #pragma unroll
      for (int nt = 0; nt < 4; ++nt)
        acc[mt][nt] = __builtin_amdgcn_mfma_f32_16x16x32_bf16(a[mt], b[nt], acc[mt][nt], 0, 0, 0);
  }

  // shuffled store: lane col c -> l = c ; r = k*16 + wq*4 + nt (4 r-contiguous -> 8B store)
  const int c = lr;
  const int rbase = k * 16 + wq * 4;
  #pragma unroll
  for (int mt = 0; mt < 4; ++mt) {
    #pragma unroll
    for (int j = 0; j < 4; ++j) {
      int brow = b0 + mt * 16 + kid * 4 + j;     // C/D: row = (lane>>4)*4 + reg
      short4v v;
      #pragma unroll
      for (int nt = 0; nt < 4; ++nt) v[nt] = f2bf(acc[mt][nt][j]);
      *(short4v*)(inter + (size_t)brow * 4096 + c * 256 + rbase) = v;
    }
  }
}

// ---------------- stage 2: out[b][s*16+l] = sum_r inter[b][l][r] * w2[l][s][r] ----------------
// 32x32x16 MFMA, l-inner (8 l per lane) so writes are dense 32B sectors per lane.
__global__ __launch_bounds__(256, 2) void stage2_kernel(
    const short* __restrict__ inter, const short* __restrict__ w2b, float* __restrict__ out) {
  __shared__ short lds[32768];          // A tile: [0,16384) shorts, B tile: [16384,32768)
  const int tid   = threadIdx.x;
  const int lane  = tid & 63;
  const int wid   = tid >> 6;
  const int wb    = wid >> 1;           // wave-grid 2x2
  const int ws    = wid & 1;
  const int b0    = blockIdx.x * 64;
  const int s0    = blockIdx.y * 64;
  const int lbase = blockIdx.z * 8;     // l-half
  const int lrow  = lane & 31;
  const int khalf = lane >> 5;          // 0/1

  f32x16 acc[8] = {};

  for (int ck = 0; ck < 8; ++ck) {
    const int kc = ck * 32;
    // ---- reg-stage loads: 8 A pieces + 8 B pieces of 16B per thread ----
    int4v va[8], vb[8];
    #pragma unroll
    for (int j = 0; j < 8; ++j) {
      int i    = tid + j * 256;         // 16B piece index [0,2048)
      int row  = i >> 5;                // b-row (A) / s-row (B), 0..63
      int slot = i & 31;                // l*4 + r8
      int l    = slot >> 2;
      int r8   = slot & 3;
      va[j] = *(const int4v*)(inter + (size_t)(b0 + row) * 4096
                                    + (lbase + l) * 256 + kc + r8 * 8);
      vb[j] = *(const int4v*)(w2b + (size_t)(lbase + l) * 262144
                                  + (size_t)(s0 + row) * 256 + kc + r8 * 8);
    }
    __syncthreads();   // previous chunk's ds_reads complete before overwrite
    #pragma unroll
    for (int j = 0; j < 8; ++j) {
      int i    = tid + j * 256;
      int row  = i >> 5;
      int slot = i & 31;
      int dst  = (row * 512 + ((slot * 16) ^ ((row & 7) << 4))) >> 1;  // shorts, XOR-swizzled
      *(int4v*)(lds + dst)         = va[j];
      *(int4v*)(lds + 16384 + dst) = vb[j];
    }
    __syncthreads();
    // ---- compute: 8 l x 2 k-steps of 16 ----
    const int arow = wb * 32 + lrow;
    const int brow = ws * 32 + lrow;
    #pragma unroll
    for (int l = 0; l < 8; ++l) {
      #pragma unroll
      for (int kh = 0; kh < 2; ++kh) {
        int inner = l * 64 + kh * 32 + khalf * 16;
        int aoff = (arow * 512 + (inner ^ ((arow & 7) << 4))) >> 1;
        int boff = (brow * 512 + (inner ^ ((brow & 7) << 4))) >> 1;
        short8 af = *(const short8*)(lds + aoff);
        short8 bf = *(const short8*)(lds + 16384 + boff);
        acc[l] = __builtin_amdgcn_mfma_f32_32x32x16_bf16(af, bf, acc[l], 0, 0, 0);
      }
    }
  }

  // ---- epilogue: per (b,s) one lane owns 8 consecutive l -> two dense f32x4 stores ----
  const int colbase = (s0 + ws * 32 + lrow) * 16 + lbase;
  #pragma unroll
  for (int reg = 0; reg < 16; ++reg) {
    int row = b0 + wb * 32 + (reg & 3) + 8 * (reg >> 2) + 4 * khalf;  // verified 32x32 C/D map
    f32x4 lo = { acc[0][reg], acc[1][reg], acc[2][reg], acc[3][reg] };
    f32x4 hi = { acc[4][reg], acc[5][reg], acc[6][reg], acc[7][reg] };
    float* op = out + (size_t)row * 16384 + colbase;
    *(f32x4*)op       = lo;
    *(f32x4*)(op + 4) = hi;
  }
}

extern "C" void kernel_launch(void* const* d_in, const int* in_sizes, int n_in,
                              void* d_out, int out_size, void* d_ws, size_t ws_size,
                              hipStream_t stream) {
  const float* x  = (const float*)d_in[0];
  const float* w1 = (const float*)d_in[1];
  const float* w2 = (const float*)d_in[2];
  float* out = (float*)d_out;

  short* inter = (short*)d_ws;                          // 32 MB  (4096 x 16 x 256 bf16)
  short* w1b   = (short*)((char*)d_ws + (32u << 20));   //  2 MB
  short* w2b   = (short*)((char*)d_ws + (34u << 20));   //  8 MB

  cvt_kernel<<<256, 256, 0, stream>>>(w1, w1b, 1048576 / 4);
  cvt_kernel<<<1024, 256, 0, stream>>>(w2, w2b, 4194304 / 4);
  stage1_kernel<<<dim3(64, 16), 256, 0, stream>>>(x, w1b, inter);
  stage2_kernel<<<dim3(64, 16, 2), 256, 0, stream>>>(inter, w2b, out);
}